// Round 1
// baseline (411.096 us; speedup 1.0000x reference)
//
#include <hip/hip_runtime.h>
#include <hip/hip_fp16.h>
#include <stdint.h>

// Problem constants
#define Bb 8
#define Tt 4096
#define Cc 512
#define Hh 512
#define Mm (Bb*Tt)      // 32768
#define Nn (3*Hh)       // 1536
#define Kk (2*Cc)       // 1024
#define NC 64           // chunks per batch for the scan
#define LC (Tt/NC)      // 64 steps per chunk
#define XBS (Tt*Cc + Cc) // per-batch padded x stride (elems) = 2097664

typedef _Float16 half8 __attribute__((ext_vector_type(8)));
typedef float  floatx4 __attribute__((ext_vector_type(4)));

typedef const __attribute__((address_space(1))) uint32_t* gptr_t;
typedef __attribute__((address_space(3))) uint32_t* lptr_t;

__device__ __forceinline__ void g2lds16(const void* g, void* l) {
    __builtin_amdgcn_global_load_lds((gptr_t)g, (lptr_t)l, 16, 0, 0);
}

__device__ __forceinline__ float fsigmoid(float x) {
    return 1.0f / (1.0f + __expf(-x));
}
__device__ __forceinline__ float ftanh(float x) {
    return 2.0f / (1.0f + __expf(-2.0f * x)) - 1.0f;
}

// ---- x fp32 -> fp16 with 512-elem zero pad at front of each batch ----
__global__ __launch_bounds__(256) void cvt_x(const float* __restrict__ x,
                                             _Float16* __restrict__ xh) {
    int i = blockIdx.x * 256 + threadIdx.x;   // [0, XBS)
    int b = blockIdx.y;
    if (i >= XBS) return;
    _Float16 v = (_Float16)0.0f;
    if (i >= Cc) v = (_Float16)x[(long)b * (Tt*Cc) + i - Cc];
    xh[(long)b * XBS + i] = v;
}

// ---- build Bt[n][kk] = kernel_{n/512}[kk/512][kk%512][n%512] as fp16 ----
__global__ __launch_bounds__(256) void cvt_w(const float* __restrict__ zk,
                                             const float* __restrict__ fk,
                                             const float* __restrict__ ok,
                                             _Float16* __restrict__ bt) {
    int idx = blockIdx.x * 256 + threadIdx.x; // < 1536*1024
    int n  = idx >> 10;
    int kk = idx & 1023;
    int which = n >> 9;
    int h = n & 511;
    int kw = kk >> 9;
    int c = kk & 511;
    const float* src = (which == 0) ? zk : ((which == 1) ? fk : ok);
    bt[idx] = (_Float16)src[kw * (Cc*Hh) + c * Hh + h];
}

// ---- MFMA fp16 GEMM: Y[32768,1536] = A @ W, Y stored fp16 (pre-activation) ----
__global__ __launch_bounds__(256) void gemm_qrnn(const _Float16* __restrict__ xh,
                                                 const _Float16* __restrict__ bt,
                                                 _Float16* __restrict__ yh) {
    // LDS: A-tile 512 slots x 16B, then B-tile 512 slots x 16B.
    // slot s (A): kg = s>>7 (k-group of 8), m = s&127 -> holds A[m][kb+kg*8 .. +8)
    __shared__ _Float16 lds[2 * 512 * 8];

    const int tid  = threadIdx.x;
    const int lane = tid & 63;
    const int w    = tid >> 6;          // wave 0..3
    const int m0   = blockIdx.x * 128;
    const int n0   = blockIdx.y * 128;
    const int wm   = (w & 1) * 64;      // wave m-offset
    const int wn   = (w >> 1) * 64;     // wave n-offset
    const int q    = lane >> 4;         // lane quad
    const int l15  = lane & 15;

    floatx4 acc[4][4] = {};

    // Wave w stages k-group kg == w for both tiles; 2 issues (j) of 64 rows each.
    // Global rows for A: m_g = m0 + j*64 + lane  (elem = (m_g + batch)<<9 + k)
    // Global rows for B: n_g = n0 + j*64 + lane  (elem = n_g<<10 + k)
    int mg0 = m0 + lane;
    int mg1 = m0 + 64 + lane;
    long aoff0 = ((long)(mg0 + (mg0 >> 12)) << 9) + w * 8;
    long aoff1 = ((long)(mg1 + (mg1 >> 12)) << 9) + w * 8;
    long boff0 = ((long)(n0 + lane)      << 10) + w * 8;
    long boff1 = ((long)(n0 + 64 + lane) << 10) + w * 8;

    _Float16* ldsA0 = &lds[(w * 128 + 0 ) * 8];
    _Float16* ldsA1 = &lds[(w * 128 + 64) * 8];
    _Float16* ldsB0 = &lds[(512 + w * 128 + 0 ) * 8];
    _Float16* ldsB1 = &lds[(512 + w * 128 + 64) * 8];

    for (int kt = 0; kt < Kk / 32; ++kt) {
        const int kb = kt * 32;
        g2lds16(xh + aoff0 + kb, ldsA0);
        g2lds16(xh + aoff1 + kb, ldsA1);
        g2lds16(bt + boff0 + kb, ldsB0);
        g2lds16(bt + boff1 + kb, ldsB1);
        __syncthreads();

        half8 af[4], bf[4];
#pragma unroll
        for (int mi = 0; mi < 4; ++mi)
            af[mi] = *(const half8*)&lds[(q * 128 + wm + mi * 16 + l15) * 8];
#pragma unroll
        for (int ni = 0; ni < 4; ++ni)
            bf[ni] = *(const half8*)&lds[(512 + q * 128 + wn + ni * 16 + l15) * 8];

#pragma unroll
        for (int mi = 0; mi < 4; ++mi)
#pragma unroll
            for (int ni = 0; ni < 4; ++ni)
                acc[mi][ni] = __builtin_amdgcn_mfma_f32_16x16x32_f16(
                    af[mi], bf[ni], acc[mi][ni], 0, 0, 0);
        __syncthreads();
    }

    // Epilogue: C/D layout col = lane&15, row = (lane>>4)*4 + r
#pragma unroll
    for (int mi = 0; mi < 4; ++mi) {
#pragma unroll
        for (int ni = 0; ni < 4; ++ni) {
#pragma unroll
            for (int r = 0; r < 4; ++r) {
                int m = m0 + wm + mi * 16 + q * 4 + r;
                int n = n0 + wn + ni * 16 + l15;
                yh[(long)m * Nn + n] = (_Float16)acc[mi][ni][r];
            }
        }
    }
}

// ---- scan pass 1: per-chunk local scan (h_in = 0), emit prod(f) and h_end ----
__global__ __launch_bounds__(256) void scan_partial(const _Float16* __restrict__ yh,
                                                    const float* __restrict__ zb,
                                                    const float* __restrict__ fb,
                                                    float* __restrict__ pf,
                                                    float* __restrict__ he) {
    int c  = blockIdx.x >> 1;
    int hg = blockIdx.x & 1;
    int b  = blockIdx.y;
    int h  = hg * 256 + threadIdx.x;
    float zbias = zb[h], fbias = fb[h];
    float hl = 0.0f, p = 1.0f;
    long base = ((long)(b * Tt + c * LC)) * Nn;
    for (int t = 0; t < LC; ++t) {
        float yz = (float)yh[base + h] + zbias;
        float yf = (float)yh[base + 512 + h] + fbias;
        float f = fsigmoid(yf);
        float z = ftanh(yz);
        hl = f * hl + (1.0f - f) * z;
        p *= f;
        base += Nn;
    }
    int o = (b * NC + c) * Hh + h;
    pf[o] = p;
    he[o] = hl;
}

// ---- scan pass 2: sequential combine over chunks -> h_in per chunk ----
__global__ __launch_bounds__(256) void scan_combine(const float* __restrict__ pf,
                                                    const float* __restrict__ he,
                                                    float* __restrict__ hin) {
    int idx = blockIdx.x * 256 + threadIdx.x; // b*512 + h, 4096 total
    int b = idx >> 9;
    int h = idx & 511;
    float hcur = 0.0f;
    for (int c = 0; c < NC; ++c) {
        int o = (b * NC + c) * Hh + h;
        hin[o] = hcur;
        hcur = pf[o] * hcur + he[o];
    }
}

// ---- scan pass 3: redo local scan with true h_in, apply o-gate, write out ----
__global__ __launch_bounds__(256) void scan_final(const _Float16* __restrict__ yh,
                                                  const float* __restrict__ zb,
                                                  const float* __restrict__ fb,
                                                  const float* __restrict__ ob,
                                                  const float* __restrict__ hin,
                                                  float* __restrict__ out) {
    int c  = blockIdx.x >> 1;
    int hg = blockIdx.x & 1;
    int b  = blockIdx.y;
    int h  = hg * 256 + threadIdx.x;
    float zbias = zb[h], fbias = fb[h], obias = ob[h];
    float hcur = hin[(b * NC + c) * Hh + h];
    long base  = ((long)(b * Tt + c * LC)) * Nn;
    long obase = ((long)(b * Tt + c * LC)) * Hh + h;
    for (int t = 0; t < LC; ++t) {
        float yz = (float)yh[base + h] + zbias;
        float yf = (float)yh[base + 512 + h] + fbias;
        float yo = (float)yh[base + 1024 + h] + obias;
        float f = fsigmoid(yf);
        float z = ftanh(yz);
        float o = fsigmoid(yo);
        hcur = f * hcur + (1.0f - f) * z;
        out[obase] = hcur * o;
        base += Nn;
        obase += Hh;
    }
}

extern "C" void kernel_launch(void* const* d_in, const int* in_sizes, int n_in,
                              void* d_out, int out_size, void* d_ws, size_t ws_size,
                              hipStream_t stream) {
    const float* x  = (const float*)d_in[0];
    const float* zk = (const float*)d_in[1];
    const float* zbias = (const float*)d_in[2];
    const float* fk = (const float*)d_in[3];
    const float* fbias = (const float*)d_in[4];
    const float* ok = (const float*)d_in[5];
    const float* obias = (const float*)d_in[6];
    float* out = (float*)d_out;

    // Workspace layout (bytes):
    char* ws = (char*)d_ws;
    _Float16* xh = (_Float16*)ws;                       // 8*2097664*2   = 33,562,624
    _Float16* bt = (_Float16*)(ws + 33562624);          // 1536*1024*2   =  3,145,728
    _Float16* yh = (_Float16*)(ws + 36708352);          // 32768*1536*2  = 100,663,296
    float*    pf = (float*)(ws + 137371648);            // 8*64*512*4    =  1,048,576
    float*    he = (float*)(ws + 138420224);            // 1,048,576
    float*    hin= (float*)(ws + 139468800);            // 1,048,576  (end 140,517,376)

    cvt_x<<<dim3(XBS / 256, Bb), 256, 0, stream>>>(x, xh);
    cvt_w<<<dim3((Nn * Kk) / 256), 256, 0, stream>>>(zk, fk, ok, bt);
    gemm_qrnn<<<dim3(Mm / 128, Nn / 128), 256, 0, stream>>>(xh, bt, yh);
    scan_partial<<<dim3(NC * 2, Bb), 256, 0, stream>>>(yh, zbias, fbias, pf, he);
    scan_combine<<<dim3(16), 256, 0, stream>>>(pf, he, hin);
    scan_final<<<dim3(NC * 2, Bb), 256, 0, stream>>>(yh, zbias, fbias, obias, hin, out);
}